// Round 4
// baseline (375.804 us; speedup 1.0000x reference)
//
#include <hip/hip_runtime.h>

#define NN 50000
#define NE 800000
#define DF 128
#define KTOT 384
#define BM 32
#define NB ((NN + BM - 1) / BM)  // 1563

typedef __attribute__((ext_vector_type(8))) short bf16x8;
typedef __attribute__((ext_vector_type(4))) float f32x4;

// ---- workspace layout (bytes) ----
static const size_t OFF_DEG  = 0;         // u32[NN]
static const size_t OFF_OFFS = 204800;    // u32[NN+1]
static const size_t OFF_CUR  = 409600;    // u32[NN]
static const size_t OFF_CSR  = 819200;    // int2[NE]
static const size_t OFF_BCT  = 7372800;   // bf16[128][384]
// total ~7.5 MB

__device__ __forceinline__ unsigned f2bf(float f) {
    unsigned u = __float_as_uint(f);
    return (u + 0x7FFFu + ((u >> 16) & 1u)) >> 16;
}

// zero deg/cur (ALL NN entries!) + build BcT[n][k]
// (k: 0-127 = W[:, :128], 128-255 = W[:,128:], 256-383 = We)
__global__ void k_setup(const float* __restrict__ W, const float* __restrict__ We,
                        unsigned* __restrict__ deg, unsigned* __restrict__ cur,
                        unsigned short* __restrict__ BcT) {
    int idx = blockIdx.x * blockDim.x + threadIdx.x;
    if (idx < NN) { deg[idx] = 0; cur[idx] = 0; }
    if (idx < 128 * KTOT) {
        int n = idx / KTOT, k = idx - n * KTOT;
        float v;
        if (k < 128)      v = W[k * 256 + n];
        else if (k < 256) v = W[(k - 128) * 256 + 128 + n];
        else              v = We[(k - 256) * 128 + n];
        BcT[idx] = (unsigned short)f2bf(v);
    }
}

__global__ void k_hist(const int* __restrict__ rcv, unsigned* __restrict__ deg) {
    int e = blockIdx.x * blockDim.x + threadIdx.x;
    if (e < NE) atomicAdd(&deg[rcv[e]], 1u);
}

__global__ void k_scan(const unsigned* __restrict__ deg, unsigned* __restrict__ offs) {
    __shared__ unsigned sums[256];
    const int PER = (NN + 255) / 256;
    int t = threadIdx.x;
    int base = t * PER;
    unsigned s = 0;
    for (int i = 0; i < PER; ++i) {
        int idx = base + i;
        if (idx < NN) s += deg[idx];
    }
    sums[t] = s;
    __syncthreads();
    if (t == 0) {
        unsigned run = 0;
        for (int i = 0; i < 256; ++i) { unsigned v = sums[i]; sums[i] = run; run += v; }
    }
    __syncthreads();
    unsigned run = sums[t];
    for (int i = 0; i < PER; ++i) {
        int idx = base + i;
        if (idx < NN) { offs[idx] = run; run += deg[idx]; }
    }
    if (t == 255) offs[NN] = run;
}

__global__ void k_scatter(const int* __restrict__ snd, const int* __restrict__ rcv,
                          const unsigned* __restrict__ offs, unsigned* __restrict__ cur,
                          int2* __restrict__ csr) {
    int e = blockIdx.x * blockDim.x + threadIdx.x;
    if (e >= NE) return;
    int r = rcv[e];
    unsigned p = atomicAdd(&cur[r], 1u);
    csr[offs[r] + p] = make_int2(snd[e], e);
}

// fused: aggregate 32 nodes into swizzled LDS bf16 tile [32][384], then MFMA gemm
__global__ __launch_bounds__(256) void k_aggemm(
    const float* __restrict__ X, const float* __restrict__ EF,
    const unsigned* __restrict__ offs, const int2* __restrict__ csr,
    const unsigned short* __restrict__ BcT, const float* __restrict__ bW,
    const float* __restrict__ bWe, float* __restrict__ out) {
    __shared__ unsigned short As[BM * KTOT];  // 24576 B, XOR-swizzled
    __shared__ float cf_s[BM];
    const int tid = threadIdx.x;
    const int w = tid >> 6, lane = tid & 63;
    const int m0 = blockIdx.x * BM;
    char* Asb = (char*)As;

    // ---- phase A: each wave aggregates 8 nodes ----
    {
        const int half = lane >> 5;          // 0: edge p, 1: edge p+1; 0 writes An, 1 writes Ae
        const int c = (lane & 31) * 4;       // col 0..124 (float4)
        for (int t = 0; t < 8; ++t) {
            int r = w * 8 + t;
            int n = m0 + r;
            unsigned s0 = 0, s1 = 0;
            if (n < NN) { s0 = offs[n]; s1 = offs[n + 1]; }
            s0 = __builtin_amdgcn_readfirstlane(s0);
            s1 = __builtin_amdgcn_readfirstlane(s1);
            unsigned dg = s1 - s0;
            f32x4 an = {0.f, 0.f, 0.f, 0.f}, ae = {0.f, 0.f, 0.f, 0.f};
            unsigned trips = (dg + 1) >> 1;
            unsigned p = s0 + half;
#pragma unroll 2
            for (unsigned it = 0; it < trips; ++it, p += 2) {
                bool act = p < s1;
                unsigned pc = act ? p : s0;
                int2 se = csr[pc];
                f32x4 xv = *reinterpret_cast<const f32x4*>(X + (size_t)se.x * DF + c);
                f32x4 ev = *reinterpret_cast<const f32x4*>(EF + (size_t)se.y * DF + c);
                float m = act ? 1.f : 0.f;
                an += m * xv;
                ae += m * ev;
            }
#pragma unroll
            for (int q = 0; q < 4; ++q) {
                an[q] += __shfl_xor(an[q], 32);
                ae[q] += __shfl_xor(ae[q], 32);
            }
            float inv = 1.0f / ((float)dg + 1e-6f);
            f32x4 v = half ? ae : an;
            v *= inv;
            int col = (half ? 256 : 128) + c;
            unsigned pk0 = f2bf(v[0]) | (f2bf(v[1]) << 16);
            unsigned pk1 = f2bf(v[2]) | (f2bf(v[3]) << 16);
            unsigned byte = (unsigned)(r * (KTOT * 2) + col * 2) ^ ((unsigned)(r & 7) << 4);
            *reinterpret_cast<uint2*>(Asb + byte) = make_uint2(pk0, pk1);
            if (lane == 0) cf_s[r] = (float)dg * inv;
        }
    }
    // ---- phase B: X rows -> LDS cols 0..127 (bf16) ----
    for (int i = tid; i < BM * 32; i += 256) {
        int r = i >> 5, g = i & 31;
        int n = m0 + r;
        f32x4 v = {0.f, 0.f, 0.f, 0.f};
        if (n < NN) v = *reinterpret_cast<const f32x4*>(X + (size_t)n * DF + g * 4);
        unsigned pk0 = f2bf(v[0]) | (f2bf(v[1]) << 16);
        unsigned pk1 = f2bf(v[2]) | (f2bf(v[3]) << 16);
        unsigned byte = (unsigned)(r * (KTOT * 2) + g * 8) ^ ((unsigned)(r & 7) << 4);
        *reinterpret_cast<uint2*>(Asb + byte) = make_uint2(pk0, pk1);
    }
    __syncthreads();

    // ---- phase C: gemm. wave covers 16 rows x 64 cols ----
    {
        const int l15 = lane & 15, l4 = lane >> 4;
        const int rrow = (w & 1) * 16 + l15;   // A-frag row (local)
        const int n0 = (w >> 1) * 64;          // col base
        f32x4 acc[4];
#pragma unroll
        for (int ng = 0; ng < 4; ++ng) acc[ng] = (f32x4){0.f, 0.f, 0.f, 0.f};
        const unsigned short* brow = BcT + (size_t)(n0 + l15) * KTOT + l4 * 8;
        const unsigned rswz = (unsigned)(rrow & 7) << 4;
#pragma unroll
        for (int kk = 0; kk < 12; ++kk) {
            unsigned abyte = (unsigned)(rrow * (KTOT * 2) + (kk * 32 + l4 * 8) * 2) ^ rswz;
            bf16x8 a = *reinterpret_cast<const bf16x8*>(Asb + abyte);
            bf16x8 b0 = *reinterpret_cast<const bf16x8*>(brow + kk * 32);
            bf16x8 b1 = *reinterpret_cast<const bf16x8*>(brow + 16 * KTOT + kk * 32);
            bf16x8 b2 = *reinterpret_cast<const bf16x8*>(brow + 32 * KTOT + kk * 32);
            bf16x8 b3 = *reinterpret_cast<const bf16x8*>(brow + 48 * KTOT + kk * 32);
            acc[0] = __builtin_amdgcn_mfma_f32_16x16x32_bf16(a, b0, acc[0], 0, 0, 0);
            acc[1] = __builtin_amdgcn_mfma_f32_16x16x32_bf16(a, b1, acc[1], 0, 0, 0);
            acc[2] = __builtin_amdgcn_mfma_f32_16x16x32_bf16(a, b2, acc[2], 0, 0, 0);
            acc[3] = __builtin_amdgcn_mfma_f32_16x16x32_bf16(a, b3, acc[3], 0, 0, 0);
        }
        // epilogue: D row = (w&1)*16 + l4*4 + j, col = n0 + ng*16 + l15
#pragma unroll
        for (int ng = 0; ng < 4; ++ng) {
            int col = n0 + ng * 16 + l15;
            float bx = bW[col];
            float bj = bW[128 + col] + bWe[col];
#pragma unroll
            for (int j = 0; j < 4; ++j) {
                int lr = (w & 1) * 16 + l4 * 4 + j;
                int row = m0 + lr;
                if (row < NN)
                    out[(size_t)row * DF + col] = acc[ng][j] + bx + cf_s[lr] * bj;
            }
        }
    }
}

extern "C" void kernel_launch(void* const* d_in, const int* in_sizes, int n_in,
                              void* d_out, int out_size, void* d_ws, size_t ws_size,
                              hipStream_t stream) {
    const float* X   = (const float*)d_in[0];
    const int*   snd = (const int*)d_in[1];
    const int*   rcv = (const int*)d_in[2];
    const float* EF  = (const float*)d_in[3];
    const float* W   = (const float*)d_in[4];
    const float* bW  = (const float*)d_in[5];
    const float* We  = (const float*)d_in[6];
    const float* bWe = (const float*)d_in[7];
    float* out = (float*)d_out;

    char* ws = (char*)d_ws;
    unsigned* deg  = (unsigned*)(ws + OFF_DEG);
    unsigned* offs = (unsigned*)(ws + OFF_OFFS);
    unsigned* cur  = (unsigned*)(ws + OFF_CUR);
    int2*     csr  = (int2*)(ws + OFF_CSR);
    unsigned short* BcT = (unsigned short*)(ws + OFF_BCT);

    // NOTE: must cover max(NN, 128*KTOT) threads — NN zeroing was the round-3 crash
    k_setup<<<(NN + 255) / 256, 256, 0, stream>>>(W, We, deg, cur, BcT);
    k_hist<<<(NE + 255) / 256, 256, 0, stream>>>(rcv, deg);
    k_scan<<<1, 256, 0, stream>>>(deg, offs);
    k_scatter<<<(NE + 255) / 256, 256, 0, stream>>>(snd, rcv, offs, cur, csr);
    k_aggemm<<<NB, 256, 0, stream>>>(X, EF, offs, csr, BcT, bW, bWe, out);
}

// Round 5
// 253.095 us; speedup vs baseline: 1.4848x; 1.4848x over previous
//
#include <hip/hip_runtime.h>

#define NN 50000
#define NE 800000
#define DF 128
#define KTOT 384
#define BM 32
#define NB ((NN + BM - 1) / BM)   // 1563
#define SCAN_B ((NN + 255) / 256) // 196

typedef __attribute__((ext_vector_type(8))) short bf16x8;
typedef __attribute__((ext_vector_type(4))) float f32x4;

// ---- workspace layout (bytes) ----
static const size_t OFF_DEG  = 0;         // u32[NN]
static const size_t OFF_OFFS = 204800;    // u32[NN+1]
static const size_t OFF_CUR  = 409600;    // u32[NN]
static const size_t OFF_PART = 614400;    // u32[SCAN_B]
static const size_t OFF_CSR  = 819200;    // int2[NE]
static const size_t OFF_BCT  = 7372800;   // bf16[128][384]

__device__ __forceinline__ unsigned f2bf(float f) {
    unsigned u = __float_as_uint(f);
    return (u + 0x7FFFu + ((u >> 16) & 1u)) >> 16;
}

// zero deg/cur (ALL NN entries) + build BcT[n][k]
__global__ void k_setup(const float* __restrict__ W, const float* __restrict__ We,
                        unsigned* __restrict__ deg, unsigned* __restrict__ cur,
                        unsigned short* __restrict__ BcT) {
    int idx = blockIdx.x * blockDim.x + threadIdx.x;
    if (idx < NN) { deg[idx] = 0; cur[idx] = 0; }
    if (idx < 128 * KTOT) {
        int n = idx / KTOT, k = idx - n * KTOT;
        float v;
        if (k < 128)      v = W[k * 256 + n];
        else if (k < 256) v = W[(k - 128) * 256 + 128 + n];
        else              v = We[(k - 256) * 128 + n];
        BcT[idx] = (unsigned short)f2bf(v);
    }
}

__global__ void k_hist(const int* __restrict__ rcv, unsigned* __restrict__ deg) {
    int e = blockIdx.x * blockDim.x + threadIdx.x;
    if (e < NE) atomicAdd(&deg[rcv[e]], 1u);
}

// parallel scan, pass 1: coalesced per-block sums
__global__ void k_scan1(const unsigned* __restrict__ deg, unsigned* __restrict__ part) {
    int idx = blockIdx.x * 256 + threadIdx.x;
    unsigned v = (idx < NN) ? deg[idx] : 0;
#pragma unroll
    for (int o = 32; o; o >>= 1) v += __shfl_down(v, o);
    __shared__ unsigned wsum[4];
    int w = threadIdx.x >> 6, lane = threadIdx.x & 63;
    if (lane == 0) wsum[w] = v;
    __syncthreads();
    if (threadIdx.x == 0) part[blockIdx.x] = wsum[0] + wsum[1] + wsum[2] + wsum[3];
}

// pass 2: scan the 196 partials (tiny)
__global__ void k_scan2(unsigned* __restrict__ part, unsigned* __restrict__ offs) {
    __shared__ unsigned sh[SCAN_B];
    int t = threadIdx.x;
    if (t < SCAN_B) sh[t] = part[t];
    __syncthreads();
    if (t == 0) {
        unsigned run = 0;
        for (int i = 0; i < SCAN_B; ++i) { unsigned v = sh[i]; sh[i] = run; run += v; }
        offs[NN] = run;  // == NE
    }
    __syncthreads();
    if (t < SCAN_B) part[t] = sh[t];
}

// pass 3: coalesced block-local exclusive scan + base
__global__ void k_scan3(const unsigned* __restrict__ deg, const unsigned* __restrict__ part,
                        unsigned* __restrict__ offs) {
    int idx = blockIdx.x * 256 + threadIdx.x;
    unsigned v = (idx < NN) ? deg[idx] : 0;
    int w = threadIdx.x >> 6, lane = threadIdx.x & 63;
    unsigned x = v;
#pragma unroll
    for (int o = 1; o < 64; o <<= 1) {
        unsigned y = __shfl_up(x, o);
        if (lane >= o) x += y;
    }
    __shared__ unsigned wsum[4];
    if (lane == 63) wsum[w] = x;
    __syncthreads();
    unsigned base = part[blockIdx.x];
    for (int i = 0; i < w; ++i) base += wsum[i];
    if (idx < NN) offs[idx] = base + x - v;
}

__global__ void k_scatter(const int* __restrict__ snd, const int* __restrict__ rcv,
                          const unsigned* __restrict__ offs, unsigned* __restrict__ cur,
                          int2* __restrict__ csr) {
    int e = blockIdx.x * blockDim.x + threadIdx.x;
    if (e >= NE) return;
    int r = rcv[e];
    unsigned p = atomicAdd(&cur[r], 1u);
    csr[offs[r] + p] = make_int2(snd[e], e);
}

// fused: aggregate 32 nodes into swizzled LDS bf16 tile [32][384], then MFMA gemm
// 512 threads = 8 waves; phase A: wave owns 4 nodes, 16-lane quarter per edge (4 chains)
__global__ __launch_bounds__(512) void k_aggemm(
    const float* __restrict__ X, const float* __restrict__ EF,
    const unsigned* __restrict__ offs, const int2* __restrict__ csr,
    const unsigned short* __restrict__ BcT, const float* __restrict__ bW,
    const float* __restrict__ bWe, float* __restrict__ out) {
    __shared__ unsigned short As[BM * KTOT];  // 24576 B, XOR-swizzled
    __shared__ float cf_s[BM];
    const int tid = threadIdx.x;
    const int w = tid >> 6, lane = tid & 63;
    const int m0 = blockIdx.x * BM;
    char* Asb = (char*)As;

    // ---- phase A ----
    {
        const int q = lane >> 4;           // quarter: edge offset within group of 4
        const int cl = (lane & 15) * 8;    // col base, 8 floats per lane
        for (int t = 0; t < 4; ++t) {
            int r = w * 4 + t;
            int n = m0 + r;
            unsigned s0 = 0, s1 = 0;
            if (n < NN) { s0 = offs[n]; s1 = offs[n + 1]; }
            s0 = __builtin_amdgcn_readfirstlane(s0);
            s1 = __builtin_amdgcn_readfirstlane(s1);
            unsigned dg = s1 - s0;
            f32x4 an0 = {0.f,0.f,0.f,0.f}, an1 = {0.f,0.f,0.f,0.f};
            f32x4 ae0 = {0.f,0.f,0.f,0.f}, ae1 = {0.f,0.f,0.f,0.f};
            unsigned trips = (dg + 3) >> 2;
            unsigned p = s0 + q;
#pragma unroll 2
            for (unsigned it = 0; it < trips; ++it, p += 4) {
                bool act = p < s1;
                unsigned pc = act ? p : s0;
                int2 se = csr[pc];
                const float* xr = X + (size_t)se.x * DF + cl;
                const float* er = EF + (size_t)se.y * DF + cl;
                f32x4 xv0 = *reinterpret_cast<const f32x4*>(xr);
                f32x4 xv1 = *reinterpret_cast<const f32x4*>(xr + 4);
                f32x4 ev0 = *reinterpret_cast<const f32x4*>(er);
                f32x4 ev1 = *reinterpret_cast<const f32x4*>(er + 4);
                float m = act ? 1.f : 0.f;
                an0 += m * xv0; an1 += m * xv1;
                ae0 += m * ev0; ae1 += m * ev1;
            }
            // reduce across 4 quarters (xor 16, then 32)
#pragma unroll
            for (int i = 0; i < 4; ++i) {
                an0[i] += __shfl_xor(an0[i], 16); an0[i] += __shfl_xor(an0[i], 32);
                an1[i] += __shfl_xor(an1[i], 16); an1[i] += __shfl_xor(an1[i], 32);
                ae0[i] += __shfl_xor(ae0[i], 16); ae0[i] += __shfl_xor(ae0[i], 32);
                ae1[i] += __shfl_xor(ae1[i], 16); ae1[i] += __shfl_xor(ae1[i], 32);
            }
            float inv = 1.0f / ((float)dg + 1e-6f);
            if (q < 2) {
                f32x4 v0 = q ? ae0 : an0, v1 = q ? ae1 : an1;
                v0 *= inv; v1 *= inv;
                int col = (q ? 256 : 128) + cl;
                uint4 pk;
                pk.x = f2bf(v0[0]) | (f2bf(v0[1]) << 16);
                pk.y = f2bf(v0[2]) | (f2bf(v0[3]) << 16);
                pk.z = f2bf(v1[0]) | (f2bf(v1[1]) << 16);
                pk.w = f2bf(v1[2]) | (f2bf(v1[3]) << 16);
                unsigned byte = (unsigned)(r * (KTOT * 2) + col * 2) ^ ((unsigned)(r & 7) << 4);
                *reinterpret_cast<uint4*>(Asb + byte) = pk;
            }
            if (lane == 0) cf_s[r] = (float)dg * inv;
        }
    }
    // ---- phase B: X rows -> LDS cols 0..127 (bf16) ----
    for (int i = tid; i < BM * 32; i += 512) {
        int r = i >> 5, g = i & 31;
        int n = m0 + r;
        f32x4 v = {0.f, 0.f, 0.f, 0.f};
        if (n < NN) v = *reinterpret_cast<const f32x4*>(X + (size_t)n * DF + g * 4);
        unsigned pk0 = f2bf(v[0]) | (f2bf(v[1]) << 16);
        unsigned pk1 = f2bf(v[2]) | (f2bf(v[3]) << 16);
        unsigned byte = (unsigned)(r * (KTOT * 2) + g * 8) ^ ((unsigned)(r & 7) << 4);
        *reinterpret_cast<uint2*>(Asb + byte) = make_uint2(pk0, pk1);
    }
    __syncthreads();

    // ---- phase C: gemm. each of 8 waves: 16 rows x 32 cols ----
    {
        const int l15 = lane & 15, l4 = lane >> 4;
        const int rrow = (w & 1) * 16 + l15;
        const int n0 = (w >> 1) * 32;
        f32x4 acc[2];
        acc[0] = (f32x4){0.f,0.f,0.f,0.f};
        acc[1] = (f32x4){0.f,0.f,0.f,0.f};
        const unsigned short* brow = BcT + (size_t)(n0 + l15) * KTOT + l4 * 8;
        const unsigned rswz = (unsigned)(rrow & 7) << 4;
#pragma unroll
        for (int kk = 0; kk < 12; ++kk) {
            unsigned abyte = (unsigned)(rrow * (KTOT * 2) + (kk * 32 + l4 * 8) * 2) ^ rswz;
            bf16x8 a = *reinterpret_cast<const bf16x8*>(Asb + abyte);
            bf16x8 b0 = *reinterpret_cast<const bf16x8*>(brow + kk * 32);
            bf16x8 b1 = *reinterpret_cast<const bf16x8*>(brow + 16 * KTOT + kk * 32);
            acc[0] = __builtin_amdgcn_mfma_f32_16x16x32_bf16(a, b0, acc[0], 0, 0, 0);
            acc[1] = __builtin_amdgcn_mfma_f32_16x16x32_bf16(a, b1, acc[1], 0, 0, 0);
        }
#pragma unroll
        for (int ng = 0; ng < 2; ++ng) {
            int col = n0 + ng * 16 + l15;
            float bx = bW[col];
            float bj = bW[128 + col] + bWe[col];
#pragma unroll
            for (int j = 0; j < 4; ++j) {
                int lr = (w & 1) * 16 + l4 * 4 + j;
                int row = m0 + lr;
                if (row < NN)
                    out[(size_t)row * DF + col] = acc[ng][j] + bx + cf_s[lr] * bj;
            }
        }
    }
}

extern "C" void kernel_launch(void* const* d_in, const int* in_sizes, int n_in,
                              void* d_out, int out_size, void* d_ws, size_t ws_size,
                              hipStream_t stream) {
    const float* X   = (const float*)d_in[0];
    const int*   snd = (const int*)d_in[1];
    const int*   rcv = (const int*)d_in[2];
    const float* EF  = (const float*)d_in[3];
    const float* W   = (const float*)d_in[4];
    const float* bW  = (const float*)d_in[5];
    const float* We  = (const float*)d_in[6];
    const float* bWe = (const float*)d_in[7];
    float* out = (float*)d_out;

    char* ws = (char*)d_ws;
    unsigned* deg  = (unsigned*)(ws + OFF_DEG);
    unsigned* offs = (unsigned*)(ws + OFF_OFFS);
    unsigned* cur  = (unsigned*)(ws + OFF_CUR);
    unsigned* part = (unsigned*)(ws + OFF_PART);
    int2*     csr  = (int2*)(ws + OFF_CSR);
    unsigned short* BcT = (unsigned short*)(ws + OFF_BCT);

    k_setup<<<(NN + 255) / 256, 256, 0, stream>>>(W, We, deg, cur, BcT);
    k_hist<<<(NE + 255) / 256, 256, 0, stream>>>(rcv, deg);
    k_scan1<<<SCAN_B, 256, 0, stream>>>(deg, part);
    k_scan2<<<1, 256, 0, stream>>>(part, offs);
    k_scan3<<<SCAN_B, 256, 0, stream>>>(deg, part, offs);
    k_scatter<<<(NE + 255) / 256, 256, 0, stream>>>(snd, rcv, offs, cur, csr);
    k_aggemm<<<NB, 512, 0, stream>>>(X, EF, offs, csr, BcT, bW, bWe, out);
}

// Round 6
// 245.563 us; speedup vs baseline: 1.5304x; 1.0307x over previous
//
#include <hip/hip_runtime.h>

#define NN 50000
#define NE 800000
#define DF 128
#define BM 32
#define NB ((NN + BM - 1) / BM)   // 1563
#define SCAN_B ((NN + 255) / 256) // 196

typedef __attribute__((ext_vector_type(8))) short bf16x8;
typedef __attribute__((ext_vector_type(4))) float f32x4;

// ---- workspace layout (bytes) ----
static const size_t OFF_DEG  = 0;         // u32[NN]
static const size_t OFF_OFFS = 204800;    // u32[NN+1]
static const size_t OFF_PART = 409600;    // u32[SCAN_B]
static const size_t OFF_RANK = 614400;    // u32[NE]
static const size_t OFF_CSR  = 3814400;   // int2[NE]
static const size_t OFF_WT   = 10214400;  // bf16 Wt[256][128]  (Wt[n][k] = W[k][n])
static const size_t OFF_WET  = 10279936;  // bf16 WeT[128][128] (WeT[n][k] = We[k][n])
static const size_t OFF_P1   = 10312704;  // f32[50048*128]  X@W[:, :128]
static const size_t OFF_P2   = 35937280;  // bf16[50048*128] X@W[:, 128:]
// total ~48.8 MB

__device__ __forceinline__ unsigned f2bf(float f) {
    unsigned u = __float_as_uint(f);
    return (u + 0x7FFFu + ((u >> 16) & 1u)) >> 16;
}

// zero deg + build Wt / WeT (bf16 transposed weights)
__global__ void k_setup(const float* __restrict__ W, const float* __restrict__ We,
                        unsigned* __restrict__ deg, unsigned short* __restrict__ Wt,
                        unsigned short* __restrict__ WeT) {
    int idx = blockIdx.x * blockDim.x + threadIdx.x;
    if (idx < NN) deg[idx] = 0;
    if (idx < 256 * 128) {
        int n = idx >> 7, k = idx & 127;
        Wt[idx] = (unsigned short)f2bf(W[k * 256 + n]);
    }
    if (idx < 128 * 128) {
        int n = idx >> 7, k = idx & 127;
        WeT[idx] = (unsigned short)f2bf(We[k * 128 + n]);
    }
}

// P1 = X@W[:, :128] (fp32), P2 = bf16(X@W[:, 128:]); 64 rows/block, 4 waves
__global__ __launch_bounds__(256) void k_gemm1(
    const float* __restrict__ X, const unsigned short* __restrict__ Wt,
    float* __restrict__ P1, unsigned short* __restrict__ P2) {
    __shared__ unsigned short As[64 * 128];  // 16 KiB, XOR-swizzled
    const int tid = threadIdx.x;
    const int w = tid >> 6, lane = tid & 63;
    const int l15 = lane & 15, l4 = lane >> 4;
    const int m0 = blockIdx.x * 64;
    char* Asb = (char*)As;

    for (int i = tid; i < 64 * 32; i += 256) {
        int r = i >> 5, g = i & 31;
        int n = m0 + r;
        f32x4 v = {0.f, 0.f, 0.f, 0.f};
        if (n < NN) v = *reinterpret_cast<const f32x4*>(X + (size_t)n * DF + g * 4);
        unsigned pk0 = f2bf(v[0]) | (f2bf(v[1]) << 16);
        unsigned pk1 = f2bf(v[2]) | (f2bf(v[3]) << 16);
        unsigned byte = (unsigned)(r * 256 + g * 8) ^ ((unsigned)(r & 7) << 4);
        *reinterpret_cast<uint2*>(Asb + byte) = make_uint2(pk0, pk1);
    }
    __syncthreads();

    const int rrow = w * 16 + l15;
    const unsigned rswz = (unsigned)(rrow & 7) << 4;
    f32x4 acc[16];
#pragma unroll
    for (int ng = 0; ng < 16; ++ng) acc[ng] = (f32x4){0.f, 0.f, 0.f, 0.f};
#pragma unroll
    for (int kk = 0; kk < 4; ++kk) {
        unsigned abyte = (unsigned)(rrow * 256 + (kk * 32 + l4 * 8) * 2) ^ rswz;
        bf16x8 a = *reinterpret_cast<const bf16x8*>(Asb + abyte);
#pragma unroll
        for (int ng = 0; ng < 16; ++ng) {
            bf16x8 b = *reinterpret_cast<const bf16x8*>(
                Wt + (size_t)(ng * 16 + l15) * 128 + kk * 32 + l4 * 8);
            acc[ng] = __builtin_amdgcn_mfma_f32_16x16x32_bf16(a, b, acc[ng], 0, 0, 0);
        }
    }
#pragma unroll
    for (int ng = 0; ng < 16; ++ng) {
        int col = ng * 16 + l15;
#pragma unroll
        for (int j = 0; j < 4; ++j) {
            int row = m0 + w * 16 + l4 * 4 + j;
            if (row < NN) {
                if (col < 128) P1[(size_t)row * DF + col] = acc[ng][j];
                else P2[(size_t)row * DF + (col - 128)] = (unsigned short)f2bf(acc[ng][j]);
            }
        }
    }
}

// deg count + per-edge rank (makes scatter atomic-free)
__global__ void k_hist(const int* __restrict__ rcv, unsigned* __restrict__ deg,
                       unsigned* __restrict__ rank) {
    int e = blockIdx.x * blockDim.x + threadIdx.x;
    if (e < NE) rank[e] = atomicAdd(&deg[rcv[e]], 1u);
}

__global__ void k_scan1(const unsigned* __restrict__ deg, unsigned* __restrict__ part) {
    int idx = blockIdx.x * 256 + threadIdx.x;
    unsigned v = (idx < NN) ? deg[idx] : 0;
#pragma unroll
    for (int o = 32; o; o >>= 1) v += __shfl_down(v, o);
    __shared__ unsigned wsum[4];
    int w = threadIdx.x >> 6, lane = threadIdx.x & 63;
    if (lane == 0) wsum[w] = v;
    __syncthreads();
    if (threadIdx.x == 0) part[blockIdx.x] = wsum[0] + wsum[1] + wsum[2] + wsum[3];
}

__global__ void k_scan2(unsigned* __restrict__ part, unsigned* __restrict__ offs) {
    __shared__ unsigned sh[SCAN_B];
    int t = threadIdx.x;
    if (t < SCAN_B) sh[t] = part[t];
    __syncthreads();
    if (t == 0) {
        unsigned run = 0;
        for (int i = 0; i < SCAN_B; ++i) { unsigned v = sh[i]; sh[i] = run; run += v; }
        offs[NN] = run;
    }
    __syncthreads();
    if (t < SCAN_B) part[t] = sh[t];
}

__global__ void k_scan3(const unsigned* __restrict__ deg, const unsigned* __restrict__ part,
                        unsigned* __restrict__ offs) {
    int idx = blockIdx.x * 256 + threadIdx.x;
    unsigned v = (idx < NN) ? deg[idx] : 0;
    int w = threadIdx.x >> 6, lane = threadIdx.x & 63;
    unsigned x = v;
#pragma unroll
    for (int o = 1; o < 64; o <<= 1) {
        unsigned y = __shfl_up(x, o);
        if (lane >= o) x += y;
    }
    __shared__ unsigned wsum[4];
    if (lane == 63) wsum[w] = x;
    __syncthreads();
    unsigned base = part[blockIdx.x];
    for (int i = 0; i < w; ++i) base += wsum[i];
    if (idx < NN) offs[idx] = base + x - v;
}

__global__ void k_scatter(const int* __restrict__ snd, const int* __restrict__ rcv,
                          const unsigned* __restrict__ offs, const unsigned* __restrict__ rank,
                          int2* __restrict__ csr) {
    int e = blockIdx.x * blockDim.x + threadIdx.x;
    if (e >= NE) return;
    csr[offs[rcv[e]] + rank[e]] = make_int2(snd[e], e);
}

// fused: per 32-node tile, aggregate P2[senders] (fp32 sums -> XJ LDS) and EF[edges]
// (-> bf16 AeS LDS), then MFMA AeS@WeT; out = P1 + XJ + Ae@WeT + biases
__global__ __launch_bounds__(512) void k_aggemm(
    const float* __restrict__ EF, const unsigned short* __restrict__ P2,
    const float* __restrict__ P1, const unsigned* __restrict__ offs,
    const int2* __restrict__ csr, const unsigned short* __restrict__ WeT,
    const float* __restrict__ bW, const float* __restrict__ bWe,
    float* __restrict__ out) {
    __shared__ unsigned short AeS[BM * 128];  // 8 KiB, XOR-swizzled
    __shared__ float XJ[BM][128];             // 16 KiB
    __shared__ float cf_s[BM];
    const int tid = threadIdx.x;
    const int w = tid >> 6, lane = tid & 63;
    const int l15 = lane & 15, q = lane >> 4;
    const int m0 = blockIdx.x * BM;
    char* Asb = (char*)AeS;

    // ---- phase A: wave owns 4 nodes; 16-lane quarter per edge (4 chains) ----
    {
        const int cl = l15 * 8;  // 8 elements per lane (cols cl..cl+7)
        for (int t = 0; t < 4; ++t) {
            int r = w * 4 + t;
            int n = m0 + r;
            unsigned s0 = 0, s1 = 0;
            if (n < NN) { s0 = offs[n]; s1 = offs[n + 1]; }
            s0 = __builtin_amdgcn_readfirstlane(s0);
            s1 = __builtin_amdgcn_readfirstlane(s1);
            unsigned dg = s1 - s0;
            f32x4 ef0 = {0.f,0.f,0.f,0.f}, ef1 = {0.f,0.f,0.f,0.f};
            f32x4 xj0 = {0.f,0.f,0.f,0.f}, xj1 = {0.f,0.f,0.f,0.f};
            unsigned trips = (dg + 3) >> 2;
            unsigned p = s0 + q;
#pragma unroll 2
            for (unsigned it = 0; it < trips; ++it, p += 4) {
                bool act = p < s1;
                unsigned pc = act ? p : s0;
                int2 se = csr[pc];
                uint4 pu = *reinterpret_cast<const uint4*>(P2 + (size_t)se.x * DF + cl);
                const float* er = EF + (size_t)se.y * DF + cl;
                f32x4 ev0 = *reinterpret_cast<const f32x4*>(er);
                f32x4 ev1 = *reinterpret_cast<const f32x4*>(er + 4);
                float m = act ? 1.f : 0.f;
                ef0 += m * ev0; ef1 += m * ev1;
                xj0[0] += m * __uint_as_float(pu.x << 16);
                xj0[1] += m * __uint_as_float(pu.x & 0xFFFF0000u);
                xj0[2] += m * __uint_as_float(pu.y << 16);
                xj0[3] += m * __uint_as_float(pu.y & 0xFFFF0000u);
                xj1[0] += m * __uint_as_float(pu.z << 16);
                xj1[1] += m * __uint_as_float(pu.z & 0xFFFF0000u);
                xj1[2] += m * __uint_as_float(pu.w << 16);
                xj1[3] += m * __uint_as_float(pu.w & 0xFFFF0000u);
            }
#pragma unroll
            for (int i = 0; i < 4; ++i) {
                ef0[i] += __shfl_xor(ef0[i], 16); ef0[i] += __shfl_xor(ef0[i], 32);
                ef1[i] += __shfl_xor(ef1[i], 16); ef1[i] += __shfl_xor(ef1[i], 32);
                xj0[i] += __shfl_xor(xj0[i], 16); xj0[i] += __shfl_xor(xj0[i], 32);
                xj1[i] += __shfl_xor(xj1[i], 16); xj1[i] += __shfl_xor(xj1[i], 32);
            }
            float inv = 1.0f / ((float)dg + 1e-6f);
            if (q == 0) {  // Ae -> bf16 LDS (swizzled)
                ef0 *= inv; ef1 *= inv;
                uint4 pk;
                pk.x = f2bf(ef0[0]) | (f2bf(ef0[1]) << 16);
                pk.y = f2bf(ef0[2]) | (f2bf(ef0[3]) << 16);
                pk.z = f2bf(ef1[0]) | (f2bf(ef1[1]) << 16);
                pk.w = f2bf(ef1[2]) | (f2bf(ef1[3]) << 16);
                unsigned byte = (unsigned)(r * 256 + cl * 2) ^ ((unsigned)(r & 7) << 4);
                *reinterpret_cast<uint4*>(Asb + byte) = pk;
            } else if (q == 1) {  // XJ -> fp32 LDS
                xj0 *= inv; xj1 *= inv;
                *reinterpret_cast<f32x4*>(&XJ[r][cl]) = xj0;
                *reinterpret_cast<f32x4*>(&XJ[r][cl + 4]) = xj1;
            }
            if (lane == 0) cf_s[r] = (float)dg * inv;
        }
    }
    __syncthreads();

    // ---- phase C: Ae @ WeT; wave: 16 rows x 32 cols, K=128 ----
    {
        const int l4 = lane >> 4;
        const int h = w & 1;
        const int rrow = h * 16 + l15;
        const int n0 = (w >> 1) * 32;
        f32x4 acc[2];
        acc[0] = (f32x4){0.f,0.f,0.f,0.f};
        acc[1] = (f32x4){0.f,0.f,0.f,0.f};
        const unsigned rswz = (unsigned)(rrow & 7) << 4;
#pragma unroll
        for (int kk = 0; kk < 4; ++kk) {
            unsigned abyte = (unsigned)(rrow * 256 + (kk * 32 + l4 * 8) * 2) ^ rswz;
            bf16x8 a = *reinterpret_cast<const bf16x8*>(Asb + abyte);
            bf16x8 b0 = *reinterpret_cast<const bf16x8*>(
                WeT + (size_t)(n0 + l15) * 128 + kk * 32 + l4 * 8);
            bf16x8 b1 = *reinterpret_cast<const bf16x8*>(
                WeT + (size_t)(n0 + 16 + l15) * 128 + kk * 32 + l4 * 8);
            acc[0] = __builtin_amdgcn_mfma_f32_16x16x32_bf16(a, b0, acc[0], 0, 0, 0);
            acc[1] = __builtin_amdgcn_mfma_f32_16x16x32_bf16(a, b1, acc[1], 0, 0, 0);
        }
#pragma unroll
        for (int ng = 0; ng < 2; ++ng) {
            int col = n0 + ng * 16 + l15;
            float bx = bW[col];
            float bj = bW[128 + col] + bWe[col];
#pragma unroll
            for (int j = 0; j < 4; ++j) {
                int lr = h * 16 + l4 * 4 + j;
                int row = m0 + lr;
                if (row < NN)
                    out[(size_t)row * DF + col] =
                        P1[(size_t)row * DF + col] + XJ[lr][col] +
                        acc[ng][j] + bx + cf_s[lr] * bj;
            }
        }
    }
}

extern "C" void kernel_launch(void* const* d_in, const int* in_sizes, int n_in,
                              void* d_out, int out_size, void* d_ws, size_t ws_size,
                              hipStream_t stream) {
    const float* X   = (const float*)d_in[0];
    const int*   snd = (const int*)d_in[1];
    const int*   rcv = (const int*)d_in[2];
    const float* EF  = (const float*)d_in[3];
    const float* W   = (const float*)d_in[4];
    const float* bW  = (const float*)d_in[5];
    const float* We  = (const float*)d_in[6];
    const float* bWe = (const float*)d_in[7];
    float* out = (float*)d_out;

    char* ws = (char*)d_ws;
    unsigned* deg  = (unsigned*)(ws + OFF_DEG);
    unsigned* offs = (unsigned*)(ws + OFF_OFFS);
    unsigned* part = (unsigned*)(ws + OFF_PART);
    unsigned* rank = (unsigned*)(ws + OFF_RANK);
    int2*     csr  = (int2*)(ws + OFF_CSR);
    unsigned short* Wt  = (unsigned short*)(ws + OFF_WT);
    unsigned short* WeT = (unsigned short*)(ws + OFF_WET);
    float*          P1  = (float*)(ws + OFF_P1);
    unsigned short* P2  = (unsigned short*)(ws + OFF_P2);

    k_setup<<<(NN + 255) / 256, 256, 0, stream>>>(W, We, deg, Wt, WeT);
    k_gemm1<<<(NN + 63) / 64, 256, 0, stream>>>(X, Wt, P1, P2);
    k_hist<<<(NE + 255) / 256, 256, 0, stream>>>(rcv, deg, rank);
    k_scan1<<<SCAN_B, 256, 0, stream>>>(deg, part);
    k_scan2<<<1, 256, 0, stream>>>(part, offs);
    k_scan3<<<SCAN_B, 256, 0, stream>>>(deg, part, offs);
    k_scatter<<<(NE + 255) / 256, 256, 0, stream>>>(snd, rcv, offs, rank, csr);
    k_aggemm<<<NB, 512, 0, stream>>>(EF, P2, P1, offs, csr, WeT, bW, bWe, out);
}